// Round 2
// baseline (1385.596 us; speedup 1.0000x reference)
//
#include <hip/hip_runtime.h>

// HierarchicalEncoder: 6× (GCN -> BN -> ReLU) with level pooling + final linear.
// Strategy: build dst-CSR once per call (count/scan/fill), then each layer is
//   tmp = h @ W[l]           (tiled fp32 GEMM, W in LDS)
//   h   = A_hat * tmp + b    (wave-per-node gather over CSR, BN stats fused)
//   h   = relu(scale*h+shift)  (BN apply, elementwise float4)
// Pool after layers 1,3,5; final 512x384 @ 384x128 GEMM + ReLU.

#define DIM 128
#define NGRAPH 512
#define EPSV 1e-5f

// ---------------- preprocessing ----------------

__global__ __launch_bounds__(256) void k_count(const int* __restrict__ ei, int* __restrict__ cnt, int E) {
  int e = blockIdx.x * 256 + threadIdx.x;
  if (e < E) atomicAdd(&cnt[ei[E + e]], 1);
}

__global__ __launch_bounds__(512) void k_blocksum(const int* __restrict__ cnt, int* __restrict__ partial, int N) {
  __shared__ int sd[512];
  int idx = blockIdx.x * 512 + threadIdx.x;
  int v = (idx < N) ? cnt[idx] : 0;
  sd[threadIdx.x] = v;
  __syncthreads();
  for (int ofs = 256; ofs > 0; ofs >>= 1) {
    if (threadIdx.x < ofs) sd[threadIdx.x] += sd[threadIdx.x + ofs];
    __syncthreads();
  }
  if (threadIdx.x == 0) partial[blockIdx.x] = sd[0];
}

__global__ __launch_bounds__(128) void k_scanpartials(int* __restrict__ partial, int nb) {
  __shared__ int sp[128];
  int t = threadIdx.x;
  int v = (t < nb) ? partial[t] : 0;
  sp[t] = v;
  __syncthreads();
  for (int ofs = 1; ofs < 128; ofs <<= 1) {
    int a = (t >= ofs) ? sp[t - ofs] : 0;
    __syncthreads();
    sp[t] += a;
    __syncthreads();
  }
  if (t < nb) partial[t] = sp[t] - v;  // exclusive block offsets
}

__global__ __launch_bounds__(512) void k_scan_write(const int* __restrict__ cnt, const int* __restrict__ partial,
                                                    int* __restrict__ rowptr, float* __restrict__ dinv, int N) {
  __shared__ int sd[512];
  int tid = threadIdx.x;
  int idx = blockIdx.x * 512 + tid;
  int v = (idx < N) ? cnt[idx] : 0;
  sd[tid] = v;
  __syncthreads();
  for (int ofs = 1; ofs < 512; ofs <<= 1) {
    int a = (tid >= ofs) ? sd[tid - ofs] : 0;
    __syncthreads();
    sd[tid] += a;
    __syncthreads();
  }
  if (idx < N) {
    int excl = partial[blockIdx.x] + sd[tid] - v;
    rowptr[idx] = excl;
    dinv[idx] = rsqrtf((float)(v + 1));  // +1 for self loop
    if (idx == N - 1) rowptr[N] = excl + v;
  }
}

__global__ __launch_bounds__(256) void k_fill(const int* __restrict__ ei, const int* __restrict__ rowptr,
                                              int* __restrict__ cursor, const float* __restrict__ dinv,
                                              int* __restrict__ col, float* __restrict__ val, int E) {
  int e = blockIdx.x * 256 + threadIdx.x;
  if (e >= E) return;
  int s = ei[e];
  int d = ei[E + e];
  int pos = rowptr[d] + atomicAdd(&cursor[d], 1);
  col[pos] = s;
  val[pos] = dinv[s] * dinv[d];
}

__global__ __launch_bounds__(256) void k_gstart(const int* __restrict__ batch, int* __restrict__ start, int N) {
  int i = blockIdx.x * 256 + threadIdx.x;
  if (i >= N) return;
  int bi = batch[i];
  int prev = (i == 0) ? -1 : batch[i - 1];
  for (int g = prev + 1; g <= bi; ++g) start[g] = i;
  if (i == N - 1) {
    for (int g = bi + 1; g <= NGRAPH; ++g) start[g] = N;
  }
}

__global__ __launch_bounds__(512) void k_invcnt(const int* __restrict__ start, float* __restrict__ invcnt) {
  int g = threadIdx.x;
  if (g < NGRAPH) {
    int c = start[g + 1] - start[g];
    invcnt[g] = 1.0f / (float)max(c, 1);
  }
}

// ---------------- per-layer kernels ----------------

__device__ inline void fma4(float4& ar, float a, const float4& wv) {
  ar.x = fmaf(a, wv.x, ar.x);
  ar.y = fmaf(a, wv.y, ar.y);
  ar.z = fmaf(a, wv.z, ar.z);
  ar.w = fmaf(a, wv.w, ar.w);
}

// tmp[32 rows x 128] = A[32 x 128] @ W[128 x 128]; block 0 also zeroes BN-stat accumulators.
__global__ __launch_bounds__(256) void k_gemm(const float* __restrict__ A, const float* __restrict__ Wl,
                                              float* __restrict__ out, float* __restrict__ stats, int N) {
  __shared__ float sW[DIM][DIM];
  __shared__ float sH[32][DIM];
  int tid = threadIdx.x;
  if (blockIdx.x == 0) stats[tid] = 0.f;  // colsum[128], colsumsq[128]
  const float4* W4 = (const float4*)Wl;
  float4* sW4 = (float4*)&sW[0][0];
#pragma unroll
  for (int i = 0; i < 16; ++i) sW4[tid + i * 256] = W4[tid + i * 256];
  int row0 = blockIdx.x * 32;
#pragma unroll
  for (int i = 0; i < 4; ++i) {
    int fi = tid + i * 256;  // 0..1023 float4 slots, 32 per row
    int r = fi >> 5, c4 = fi & 31;
    int row = row0 + r;
    float4 v = make_float4(0.f, 0.f, 0.f, 0.f);
    if (row < N) v = ((const float4*)(A + (size_t)row * DIM))[c4];
    ((float4*)&sH[r][0])[c4] = v;
  }
  __syncthreads();
  int ct = tid & 31, rt = tid >> 5;  // 32 col-threads x 8 row-threads
  float4 acc[4];
#pragma unroll
  for (int r = 0; r < 4; ++r) acc[r] = make_float4(0.f, 0.f, 0.f, 0.f);
  for (int k4 = 0; k4 < 32; ++k4) {
    float4 wv0 = *(const float4*)&sW[4 * k4 + 0][4 * ct];
    float4 wv1 = *(const float4*)&sW[4 * k4 + 1][4 * ct];
    float4 wv2 = *(const float4*)&sW[4 * k4 + 2][4 * ct];
    float4 wv3 = *(const float4*)&sW[4 * k4 + 3][4 * ct];
#pragma unroll
    for (int r = 0; r < 4; ++r) {
      float4 av = *(const float4*)&sH[rt + 8 * r][4 * k4];
      fma4(acc[r], av.x, wv0);
      fma4(acc[r], av.y, wv1);
      fma4(acc[r], av.z, wv2);
      fma4(acc[r], av.w, wv3);
    }
  }
#pragma unroll
  for (int r = 0; r < 4; ++r) {
    int row = row0 + rt + 8 * r;
    if (row < N) *(float4*)(out + (size_t)row * DIM + 4 * ct) = acc[r];
  }
}

// h[i] = sum_{e in CSR(i)} val_e * tmp[col_e] + dinv[i]^2 * tmp[i] + b; fused BN-stat accumulation.
__global__ __launch_bounds__(256) void k_agg(const float* __restrict__ tmp, const int* __restrict__ rowptr,
                                             const int* __restrict__ col, const float* __restrict__ val,
                                             const float* __restrict__ dinv, const float* __restrict__ bias,
                                             float* __restrict__ hout, float* __restrict__ stats, int N) {
  int lane = threadIdx.x & 63;
  int wid = threadIdx.x >> 6;
  int gwave = blockIdx.x * 4 + wid;
  int nwaves = gridDim.x * 4;
  float bx = bias[2 * lane], by = bias[2 * lane + 1];
  float sum0 = 0.f, sum1 = 0.f, sq0 = 0.f, sq1 = 0.f;
  for (int i = gwave; i < N; i += nwaves) {
    float di = dinv[i];
    float self = di * di;
    float2 t0 = ((const float2*)(tmp + (size_t)i * DIM))[lane];
    float ax = self * t0.x, ay = self * t0.y;
    int beg = rowptr[i], end = rowptr[i + 1];
    for (int e0 = beg; e0 < end; e0 += 64) {
      int e = e0 + lane;
      int s = 0;
      float v = 0.f;
      if (e < end) {
        s = col[e];
        v = val[e];
      }
      int m = min(64, end - e0);
      for (int j = 0; j < m; ++j) {
        int sj = __shfl(s, j);
        float vj = __shfl(v, j);
        float2 t = ((const float2*)(tmp + (size_t)sj * DIM))[lane];
        ax = fmaf(vj, t.x, ax);
        ay = fmaf(vj, t.y, ay);
      }
    }
    ax += bx;
    ay += by;
    ((float2*)(hout + (size_t)i * DIM))[lane] = make_float2(ax, ay);
    sum0 += ax;
    sum1 += ay;
    sq0 = fmaf(ax, ax, sq0);
    sq1 = fmaf(ay, ay, sq1);
  }
  __shared__ float red[256][4];
  red[threadIdx.x][0] = sum0;
  red[threadIdx.x][1] = sum1;
  red[threadIdx.x][2] = sq0;
  red[threadIdx.x][3] = sq1;
  __syncthreads();
  if (threadIdx.x < 64) {
    int l = threadIdx.x;
    float a0 = red[l][0] + red[64 + l][0] + red[128 + l][0] + red[192 + l][0];
    float a1 = red[l][1] + red[64 + l][1] + red[128 + l][1] + red[192 + l][1];
    float q0 = red[l][2] + red[64 + l][2] + red[128 + l][2] + red[192 + l][2];
    float q1 = red[l][3] + red[64 + l][3] + red[128 + l][3] + red[192 + l][3];
    atomicAdd(&stats[2 * l], a0);
    atomicAdd(&stats[2 * l + 1], a1);
    atomicAdd(&stats[DIM + 2 * l], q0);
    atomicAdd(&stats[DIM + 2 * l + 1], q1);
  }
}

__global__ __launch_bounds__(128) void k_bnstat(float* __restrict__ stats, const float* __restrict__ gamma,
                                                const float* __restrict__ beta, int N) {
  int c = threadIdx.x;
  float invN = 1.f / (float)N;
  float mu = stats[c] * invN;
  float var = stats[DIM + c] * invN - mu * mu;
  float rstd = rsqrtf(var + EPSV);
  float sc = gamma[c] * rstd;
  stats[2 * DIM + c] = sc;
  stats[3 * DIM + c] = beta[c] - mu * sc;
}

__global__ __launch_bounds__(256) void k_bnapply(float* __restrict__ h, const float* __restrict__ stats, int N) {
  int idx = blockIdx.x * 256 + threadIdx.x;  // float4 index
  if (idx >= N * (DIM / 4)) return;
  int c4 = idx & 31;
  float4 sc = ((const float4*)(stats + 2 * DIM))[c4];
  float4 sh = ((const float4*)(stats + 3 * DIM))[c4];
  float4 v = ((const float4*)h)[idx];
  v.x = fmaxf(fmaf(v.x, sc.x, sh.x), 0.f);
  v.y = fmaxf(fmaf(v.y, sc.y, sh.y), 0.f);
  v.z = fmaxf(fmaf(v.z, sc.z, sh.z), 0.f);
  v.w = fmaxf(fmaf(v.w, sc.w, sh.w), 0.f);
  ((float4*)h)[idx] = v;
}

__global__ __launch_bounds__(512) void k_pool(const float* __restrict__ h, const int* __restrict__ start,
                                              const float* __restrict__ invcnt, float* __restrict__ pooled,
                                              int level) {
  int g = blockIdx.x;
  int s = start[g], e = start[g + 1];
  int c = threadIdx.x & 127;
  int stripe = threadIdx.x >> 7;  // 0..3
  float acc = 0.f;
  for (int r = s + stripe; r < e; r += 4) acc += h[(size_t)r * DIM + c];
  __shared__ float red[4][DIM];
  red[stripe][c] = acc;
  __syncthreads();
  if (threadIdx.x < DIM) {
    float v = (red[0][c] + red[1][c] + red[2][c] + red[3][c]) * invcnt[g];
    pooled[(size_t)g * (3 * DIM) + level * DIM + c] = v;
  }
}

__global__ __launch_bounds__(512) void k_final(const float* __restrict__ pooled, const float* __restrict__ Wf,
                                               const float* __restrict__ bf, float* __restrict__ out) {
  int t = blockIdx.x * 512 + threadIdx.x;
  if (t >= NGRAPH * DIM) return;
  int j = t & (DIM - 1);
  int i = t >> 7;
  const float* prow = pooled + (size_t)i * (3 * DIM);
  float acc = bf[j];
  for (int k = 0; k < 3 * DIM; ++k) acc = fmaf(prow[k], Wf[(size_t)k * DIM + j], acc);
  out[t] = fmaxf(acc, 0.f);
}

// ---------------- launcher ----------------

extern "C" void kernel_launch(void* const* d_in, const int* in_sizes, int n_in,
                              void* d_out, int out_size, void* d_ws, size_t ws_size,
                              hipStream_t stream) {
  const float* x = (const float*)d_in[0];
  const int* ei = (const int*)d_in[1];
  const int* batch = (const int*)d_in[2];
  const float* W = (const float*)d_in[3];
  const float* b = (const float*)d_in[4];
  const float* gamma = (const float*)d_in[5];
  const float* beta = (const float*)d_in[6];
  const float* Wf = (const float*)d_in[7];
  const float* bf = (const float*)d_in[8];
  float* out = (float*)d_out;

  const int N = in_sizes[0] / DIM;   // 50000
  const int E = in_sizes[1] / 2;     // 800000

  char* base = (char*)d_ws;
  size_t off = 0;
  auto alloc = [&](size_t bytes) -> char* {
    char* p = base + off;
    off += (bytes + 255) & ~(size_t)255;
    return p;
  };
  float* h      = (float*)alloc((size_t)N * DIM * 4);
  float* tmp    = (float*)alloc((size_t)N * DIM * 4);
  int* cnt      = (int*)alloc((size_t)N * 4);
  int* cursor   = (int*)alloc((size_t)N * 4);
  int* rowptr   = (int*)alloc((size_t)(N + 1) * 4);
  int* partial  = (int*)alloc(256 * 4);
  float* dinv   = (float*)alloc((size_t)N * 4);
  int* colb     = (int*)alloc((size_t)E * 4);
  float* valb   = (float*)alloc((size_t)E * 4);
  float* stats  = (float*)alloc(4 * DIM * 4);  // colsum|colsumsq|scale|shift
  int* start    = (int*)alloc((NGRAPH + 1) * 4);
  float* invcnt = (float*)alloc(NGRAPH * 4);
  float* pooled = (float*)alloc((size_t)NGRAPH * 3 * DIM * 4);
  (void)ws_size;

  (void)hipMemsetAsync(cnt, 0, (size_t)N * 4, stream);
  (void)hipMemsetAsync(cursor, 0, (size_t)N * 4, stream);

  int nbScan = (N + 511) / 512;  // 98
  k_count<<<(E + 255) / 256, 256, 0, stream>>>(ei, cnt, E);
  k_blocksum<<<nbScan, 512, 0, stream>>>(cnt, partial, N);
  k_scanpartials<<<1, 128, 0, stream>>>(partial, nbScan);
  k_scan_write<<<nbScan, 512, 0, stream>>>(cnt, partial, rowptr, dinv, N);
  k_fill<<<(E + 255) / 256, 256, 0, stream>>>(ei, rowptr, cursor, dinv, colb, valb, E);
  k_gstart<<<(N + 255) / 256, 256, 0, stream>>>(batch, start, N);
  k_invcnt<<<1, 512, 0, stream>>>(start, invcnt);

  int gemmGrid = (N + 31) / 32;
  for (int l = 0; l < 6; ++l) {
    const float* hin = (l == 0) ? x : h;
    k_gemm<<<gemmGrid, 256, 0, stream>>>(hin, W + (size_t)l * DIM * DIM, tmp, stats, N);
    k_agg<<<2048, 256, 0, stream>>>(tmp, rowptr, colb, valb, dinv, b + (size_t)l * DIM, h, stats, N);
    k_bnstat<<<1, 128, 0, stream>>>(stats, gamma + (size_t)l * DIM, beta + (size_t)l * DIM, N);
    k_bnapply<<<(N * (DIM / 4) + 255) / 256, 256, 0, stream>>>(h, stats, N);
    if (l & 1) k_pool<<<NGRAPH, 512, 0, stream>>>(h, start, invcnt, pooled, l >> 1);
  }
  k_final<<<(NGRAPH * DIM + 511) / 512, 512, 0, stream>>>(pooled, Wf, bf, out);
}

// Round 4
// 1301.869 us; speedup vs baseline: 1.0643x; 1.0643x over previous
//
#include <hip/hip_runtime.h>

// HierarchicalEncoder: 6× (GCN -> BN -> ReLU) with level pooling + final linear.
// dst-CSR built once per call; per layer:
//   tmp = BNReLU(h) @ W[l]   (fp32 GEMM, BN of PREVIOUS layer fused into A staging)
//   h   = A_hat * tmp + b    (wave-per-node gather, 4-wide batched loads, BN stats fused)
// h is always PRE-BN; consumers (next gemm, pool) apply scale/shift+relu on the fly.

#define DIM 128
#define NGRAPH 512
#define EPSV 1e-5f

// ---------------- preprocessing ----------------

__global__ __launch_bounds__(256) void k_count(const int* __restrict__ ei, int* __restrict__ cnt, int E) {
  int e = blockIdx.x * 256 + threadIdx.x;
  if (e < E) atomicAdd(&cnt[ei[E + e]], 1);
}

__global__ __launch_bounds__(512) void k_blocksum(const int* __restrict__ cnt, int* __restrict__ partial, int N) {
  __shared__ int sd[512];
  int idx = blockIdx.x * 512 + threadIdx.x;
  int v = (idx < N) ? cnt[idx] : 0;
  sd[threadIdx.x] = v;
  __syncthreads();
  for (int ofs = 256; ofs > 0; ofs >>= 1) {
    if (threadIdx.x < ofs) sd[threadIdx.x] += sd[threadIdx.x + ofs];
    __syncthreads();
  }
  if (threadIdx.x == 0) partial[blockIdx.x] = sd[0];
}

__global__ __launch_bounds__(128) void k_scanpartials(int* __restrict__ partial, int nb) {
  __shared__ int sp[128];
  int t = threadIdx.x;
  int v = (t < nb) ? partial[t] : 0;
  sp[t] = v;
  __syncthreads();
  for (int ofs = 1; ofs < 128; ofs <<= 1) {
    int a = (t >= ofs) ? sp[t - ofs] : 0;
    __syncthreads();
    sp[t] += a;
    __syncthreads();
  }
  if (t < nb) partial[t] = sp[t] - v;  // exclusive block offsets
}

__global__ __launch_bounds__(512) void k_scan_write(const int* __restrict__ cnt, const int* __restrict__ partial,
                                                    int* __restrict__ rowptr, float* __restrict__ dinv, int N) {
  __shared__ int sd[512];
  int tid = threadIdx.x;
  int idx = blockIdx.x * 512 + tid;
  int v = (idx < N) ? cnt[idx] : 0;
  sd[tid] = v;
  __syncthreads();
  for (int ofs = 1; ofs < 512; ofs <<= 1) {
    int a = (tid >= ofs) ? sd[tid - ofs] : 0;
    __syncthreads();
    sd[tid] += a;
    __syncthreads();
  }
  if (idx < N) {
    int excl = partial[blockIdx.x] + sd[tid] - v;
    rowptr[idx] = excl;
    dinv[idx] = rsqrtf((float)(v + 1));  // +1 for self loop
    if (idx == N - 1) rowptr[N] = excl + v;
  }
}

__global__ __launch_bounds__(256) void k_fill(const int* __restrict__ ei, const int* __restrict__ rowptr,
                                              int* __restrict__ cursor, const float* __restrict__ dinv,
                                              int2* __restrict__ edges, int E) {
  int e = blockIdx.x * 256 + threadIdx.x;
  if (e >= E) return;
  int s = ei[e];
  int d = ei[E + e];
  int pos = rowptr[d] + atomicAdd(&cursor[d], 1);
  edges[pos] = make_int2(s, __float_as_int(dinv[s] * dinv[d]));
}

__global__ __launch_bounds__(256) void k_gstart(const int* __restrict__ batch, int* __restrict__ start, int N) {
  int i = blockIdx.x * 256 + threadIdx.x;
  if (i >= N) return;
  int bi = batch[i];
  int prev = (i == 0) ? -1 : batch[i - 1];
  for (int g = prev + 1; g <= bi; ++g) start[g] = i;
  if (i == N - 1) {
    for (int g = bi + 1; g <= NGRAPH; ++g) start[g] = N;
  }
}

__global__ __launch_bounds__(512) void k_invcnt(const int* __restrict__ start, float* __restrict__ invcnt) {
  int g = threadIdx.x;
  if (g < NGRAPH) {
    int c = start[g + 1] - start[g];
    invcnt[g] = 1.0f / (float)max(c, 1);
  }
}

// ---------------- per-layer kernels ----------------

__device__ inline void fma4(float4& ar, float a, const float4& wv) {
  ar.x = fmaf(a, wv.x, ar.x);
  ar.y = fmaf(a, wv.y, ar.y);
  ar.z = fmaf(a, wv.z, ar.z);
  ar.w = fmaf(a, wv.w, ar.w);
}

// tmp[32 x 128] = act(A[32 x 128]) @ W[128 x 128]; act = relu(sc*a+sh) if scsh, else identity.
// Block 0 also zeroes the BN-stat accumulators (stats[0..255]).
__global__ __launch_bounds__(256) void k_gemm(const float* __restrict__ A, const float* __restrict__ Wl,
                                              const float* __restrict__ scsh,  // stats+256 | nullptr
                                              float* __restrict__ out, float* __restrict__ stats, int N) {
  __shared__ float sW[DIM][DIM];
  __shared__ float sH[32][DIM];
  int tid = threadIdx.x;
  if (blockIdx.x == 0) stats[tid] = 0.f;  // colsum[128], colsumsq[128]
  const float4* W4 = (const float4*)Wl;
  float4* sW4 = (float4*)&sW[0][0];
#pragma unroll
  for (int i = 0; i < 16; ++i) sW4[tid + i * 256] = W4[tid + i * 256];
  int row0 = blockIdx.x * 32;
#pragma unroll
  for (int i = 0; i < 4; ++i) {
    int fi = tid + i * 256;  // 0..1023 float4 slots, 32 per row
    int r = fi >> 5, c4 = fi & 31;
    int row = row0 + r;
    float4 v = make_float4(0.f, 0.f, 0.f, 0.f);
    if (row < N) v = ((const float4*)(A + (size_t)row * DIM))[c4];
    if (scsh) {
      float4 sc = ((const float4*)scsh)[c4];
      float4 sh = ((const float4*)(scsh + DIM))[c4];
      v.x = fmaxf(fmaf(v.x, sc.x, sh.x), 0.f);
      v.y = fmaxf(fmaf(v.y, sc.y, sh.y), 0.f);
      v.z = fmaxf(fmaf(v.z, sc.z, sh.z), 0.f);
      v.w = fmaxf(fmaf(v.w, sc.w, sh.w), 0.f);
    }
    ((float4*)&sH[r][0])[c4] = v;
  }
  __syncthreads();
  int ct = tid & 31, rt = tid >> 5;  // 32 col-threads x 8 row-threads
  float4 acc[4];
#pragma unroll
  for (int r = 0; r < 4; ++r) acc[r] = make_float4(0.f, 0.f, 0.f, 0.f);
  for (int k4 = 0; k4 < 32; ++k4) {
    float4 wv0 = *(const float4*)&sW[4 * k4 + 0][4 * ct];
    float4 wv1 = *(const float4*)&sW[4 * k4 + 1][4 * ct];
    float4 wv2 = *(const float4*)&sW[4 * k4 + 2][4 * ct];
    float4 wv3 = *(const float4*)&sW[4 * k4 + 3][4 * ct];
#pragma unroll
    for (int r = 0; r < 4; ++r) {
      float4 av = *(const float4*)&sH[rt + 8 * r][4 * k4];
      fma4(acc[r], av.x, wv0);
      fma4(acc[r], av.y, wv1);
      fma4(acc[r], av.z, wv2);
      fma4(acc[r], av.w, wv3);
    }
  }
#pragma unroll
  for (int r = 0; r < 4; ++r) {
    int row = row0 + rt + 8 * r;
    if (row < N) *(float4*)(out + (size_t)row * DIM + 4 * ct) = acc[r];
  }
}

// h[i] = sum_e val_e * tmp[col_e] + dinv[i]^2 * tmp[i] + b; BN-stat accumulation fused.
// Inner gather batched 4-wide for memory-level parallelism.
__global__ __launch_bounds__(256) void k_agg(const float* __restrict__ tmp, const int* __restrict__ rowptr,
                                             const int2* __restrict__ edges, const float* __restrict__ dinv,
                                             const float* __restrict__ bias, float* __restrict__ hout,
                                             float* __restrict__ stats, int N) {
  int lane = threadIdx.x & 63;
  int wid = threadIdx.x >> 6;
  int gwave = blockIdx.x * 4 + wid;
  int nwaves = gridDim.x * 4;
  float bx = bias[2 * lane], by = bias[2 * lane + 1];
  float sum0 = 0.f, sum1 = 0.f, sq0 = 0.f, sq1 = 0.f;
  for (int i = gwave; i < N; i += nwaves) {
    float di = dinv[i];
    float self = di * di;
    float2 t0 = ((const float2*)(tmp + (size_t)i * DIM))[lane];
    float ax = self * t0.x, ay = self * t0.y;
    int beg = rowptr[i], end = rowptr[i + 1];
    for (int e0 = beg; e0 < end; e0 += 64) {
      int e = e0 + lane;
      int s = 0;
      float v = 0.f;
      if (e < end) {
        int2 ev = edges[e];
        s = ev.x;
        v = __int_as_float(ev.y);
      }
      int m = min(64, end - e0);
      int j = 0;
      for (; j + 4 <= m; j += 4) {
        int s0 = __shfl(s, j), s1 = __shfl(s, j + 1), s2 = __shfl(s, j + 2), s3 = __shfl(s, j + 3);
        float v0 = __shfl(v, j), v1 = __shfl(v, j + 1), v2 = __shfl(v, j + 2), v3 = __shfl(v, j + 3);
        float2 ta = ((const float2*)(tmp + (size_t)s0 * DIM))[lane];
        float2 tb = ((const float2*)(tmp + (size_t)s1 * DIM))[lane];
        float2 tc = ((const float2*)(tmp + (size_t)s2 * DIM))[lane];
        float2 td = ((const float2*)(tmp + (size_t)s3 * DIM))[lane];
        ax = fmaf(v0, ta.x, ax);
        ay = fmaf(v0, ta.y, ay);
        ax = fmaf(v1, tb.x, ax);
        ay = fmaf(v1, tb.y, ay);
        ax = fmaf(v2, tc.x, ax);
        ay = fmaf(v2, tc.y, ay);
        ax = fmaf(v3, td.x, ax);
        ay = fmaf(v3, td.y, ay);
      }
      for (; j < m; ++j) {
        int sj = __shfl(s, j);
        float vj = __shfl(v, j);
        float2 t = ((const float2*)(tmp + (size_t)sj * DIM))[lane];
        ax = fmaf(vj, t.x, ax);
        ay = fmaf(vj, t.y, ay);
      }
    }
    ax += bx;
    ay += by;
    ((float2*)(hout + (size_t)i * DIM))[lane] = make_float2(ax, ay);
    sum0 += ax;
    sum1 += ay;
    sq0 = fmaf(ax, ax, sq0);
    sq1 = fmaf(ay, ay, sq1);
  }
  __shared__ float red[256][4];
  red[threadIdx.x][0] = sum0;
  red[threadIdx.x][1] = sum1;
  red[threadIdx.x][2] = sq0;
  red[threadIdx.x][3] = sq1;
  __syncthreads();
  if (threadIdx.x < 64) {
    int l = threadIdx.x;
    float a0 = red[l][0] + red[64 + l][0] + red[128 + l][0] + red[192 + l][0];
    float a1 = red[l][1] + red[64 + l][1] + red[128 + l][1] + red[192 + l][1];
    float q0 = red[l][2] + red[64 + l][2] + red[128 + l][2] + red[192 + l][2];
    float q1 = red[l][3] + red[64 + l][3] + red[128 + l][3] + red[192 + l][3];
    atomicAdd(&stats[2 * l], a0);
    atomicAdd(&stats[2 * l + 1], a1);
    atomicAdd(&stats[DIM + 2 * l], q0);
    atomicAdd(&stats[DIM + 2 * l + 1], q1);
  }
}

__global__ __launch_bounds__(128) void k_bnstat(float* __restrict__ stats, const float* __restrict__ gamma,
                                                const float* __restrict__ beta, int N) {
  int c = threadIdx.x;
  float invN = 1.f / (float)N;
  float mu = stats[c] * invN;
  float var = stats[DIM + c] * invN - mu * mu;
  float rstd = rsqrtf(var + EPSV);
  float sc = gamma[c] * rstd;
  stats[2 * DIM + c] = sc;
  stats[3 * DIM + c] = beta[c] - mu * sc;
}

// pool mean of relu(sc*h+sh) per graph
__global__ __launch_bounds__(512) void k_pool(const float* __restrict__ h, const int* __restrict__ start,
                                              const float* __restrict__ invcnt, const float* __restrict__ scsh,
                                              float* __restrict__ pooled, int level) {
  int g = blockIdx.x;
  int s = start[g], e = start[g + 1];
  int c = threadIdx.x & 127;
  int stripe = threadIdx.x >> 7;  // 0..3
  float sc = scsh[c], sh = scsh[DIM + c];
  float acc = 0.f;
  for (int r = s + stripe; r < e; r += 4) acc += fmaxf(fmaf(h[(size_t)r * DIM + c], sc, sh), 0.f);
  __shared__ float red[4][DIM];
  red[stripe][c] = acc;
  __syncthreads();
  if (threadIdx.x < DIM) {
    float v = (red[0][c] + red[1][c] + red[2][c] + red[3][c]) * invcnt[g];
    pooled[(size_t)g * (3 * DIM) + level * DIM + c] = v;
  }
}

__global__ __launch_bounds__(512) void k_final(const float* __restrict__ pooled, const float* __restrict__ Wf,
                                               const float* __restrict__ bf, float* __restrict__ out) {
  int t = blockIdx.x * 512 + threadIdx.x;
  if (t >= NGRAPH * DIM) return;
  int j = t & (DIM - 1);
  int i = t >> 7;
  const float* prow = pooled + (size_t)i * (3 * DIM);
  float acc = bf[j];
  for (int k = 0; k < 3 * DIM; ++k) acc = fmaf(prow[k], Wf[(size_t)k * DIM + j], acc);
  out[t] = fmaxf(acc, 0.f);
}

// ---------------- launcher ----------------

extern "C" void kernel_launch(void* const* d_in, const int* in_sizes, int n_in,
                              void* d_out, int out_size, void* d_ws, size_t ws_size,
                              hipStream_t stream) {
  const float* x = (const float*)d_in[0];
  const int* ei = (const int*)d_in[1];
  const int* batch = (const int*)d_in[2];
  const float* W = (const float*)d_in[3];
  const float* b = (const float*)d_in[4];
  const float* gamma = (const float*)d_in[5];
  const float* beta = (const float*)d_in[6];
  const float* Wf = (const float*)d_in[7];
  const float* bf = (const float*)d_in[8];
  float* out = (float*)d_out;

  const int N = in_sizes[0] / DIM;   // 50000
  const int E = in_sizes[1] / 2;     // 800000

  char* base = (char*)d_ws;
  size_t off = 0;
  auto alloc = [&](size_t bytes) -> char* {
    char* p = base + off;
    off += (bytes + 255) & ~(size_t)255;
    return p;
  };
  float* h      = (float*)alloc((size_t)N * DIM * 4);
  float* tmp    = (float*)alloc((size_t)N * DIM * 4);
  int* cnt      = (int*)alloc((size_t)N * 4);
  int* cursor   = (int*)alloc((size_t)N * 4);
  int* rowptr   = (int*)alloc((size_t)(N + 1) * 4);
  int* partial  = (int*)alloc(256 * 4);
  float* dinv   = (float*)alloc((size_t)N * 4);
  int2* edges   = (int2*)alloc((size_t)E * 8);
  float* stats  = (float*)alloc(4 * DIM * 4);  // colsum|colsumsq|scale|shift
  int* start    = (int*)alloc((NGRAPH + 1) * 4);
  float* invcnt = (float*)alloc(NGRAPH * 4);
  float* pooled = (float*)alloc((size_t)NGRAPH * 3 * DIM * 4);
  (void)ws_size;

  (void)hipMemsetAsync(cnt, 0, (size_t)N * 4, stream);
  (void)hipMemsetAsync(cursor, 0, (size_t)N * 4, stream);

  int nbScan = (N + 511) / 512;  // 98
  k_count<<<(E + 255) / 256, 256, 0, stream>>>(ei, cnt, E);
  k_blocksum<<<nbScan, 512, 0, stream>>>(cnt, partial, N);
  k_scanpartials<<<1, 128, 0, stream>>>(partial, nbScan);
  k_scan_write<<<nbScan, 512, 0, stream>>>(cnt, partial, rowptr, dinv, N);
  k_fill<<<(E + 255) / 256, 256, 0, stream>>>(ei, rowptr, cursor, dinv, edges, E);
  k_gstart<<<(N + 255) / 256, 256, 0, stream>>>(batch, start, N);
  k_invcnt<<<1, 512, 0, stream>>>(start, invcnt);

  int gemmGrid = (N + 31) / 32;
  for (int l = 0; l < 6; ++l) {
    const float* hin = (l == 0) ? x : h;
    const float* scsh = (l == 0) ? nullptr : stats + 2 * DIM;
    k_gemm<<<gemmGrid, 256, 0, stream>>>(hin, W + (size_t)l * DIM * DIM, scsh, tmp, stats, N);
    k_agg<<<2048, 256, 0, stream>>>(tmp, rowptr, edges, dinv, b + (size_t)l * DIM, h, stats, N);
    k_bnstat<<<1, 128, 0, stream>>>(stats, gamma + (size_t)l * DIM, beta + (size_t)l * DIM, N);
    if (l & 1) k_pool<<<NGRAPH, 512, 0, stream>>>(h, start, invcnt, stats + 2 * DIM, pooled, l >> 1);
  }
  k_final<<<(NGRAPH * DIM + 511) / 512, 512, 0, stream>>>(pooled, Wf, bf, out);
}

// Round 5
// 1161.847 us; speedup vs baseline: 1.1926x; 1.1205x over previous
//
#include <hip/hip_runtime.h>
#include <hip/hip_fp16.h>

// HierarchicalEncoder: 6× (GCN -> BN -> ReLU) with level pooling + final linear.
// dst-CSR built once per call; per layer:
//   tmp16 = BNReLU(h) @ W[l]  (fp32 GEMM, A-staging applies prev BN; OUTPUT fp16)
//   h     = A_hat * tmp16 + b (wave-per-node gather, 8-wide batched 4B loads, BN stats fused)
// h stays PRE-BN fp32; consumers (next gemm, pool) apply scale/shift+relu on the fly.

#define DIM 128
#define NGRAPH 512
#define EPSV 1e-5f

// ---------------- preprocessing ----------------

__global__ __launch_bounds__(256) void k_count(const int* __restrict__ ei, int* __restrict__ cnt, int E) {
  int e = blockIdx.x * 256 + threadIdx.x;
  if (e < E) atomicAdd(&cnt[ei[E + e]], 1);
}

__global__ __launch_bounds__(512) void k_blocksum(const int* __restrict__ cnt, int* __restrict__ partial, int N) {
  __shared__ int sd[512];
  int idx = blockIdx.x * 512 + threadIdx.x;
  int v = (idx < N) ? cnt[idx] : 0;
  sd[threadIdx.x] = v;
  __syncthreads();
  for (int ofs = 256; ofs > 0; ofs >>= 1) {
    if (threadIdx.x < ofs) sd[threadIdx.x] += sd[threadIdx.x + ofs];
    __syncthreads();
  }
  if (threadIdx.x == 0) partial[blockIdx.x] = sd[0];
}

__global__ __launch_bounds__(128) void k_scanpartials(int* __restrict__ partial, int nb) {
  __shared__ int sp[128];
  int t = threadIdx.x;
  int v = (t < nb) ? partial[t] : 0;
  sp[t] = v;
  __syncthreads();
  for (int ofs = 1; ofs < 128; ofs <<= 1) {
    int a = (t >= ofs) ? sp[t - ofs] : 0;
    __syncthreads();
    sp[t] += a;
    __syncthreads();
  }
  if (t < nb) partial[t] = sp[t] - v;  // exclusive block offsets
}

__global__ __launch_bounds__(512) void k_scan_write(const int* __restrict__ cnt, const int* __restrict__ partial,
                                                    int* __restrict__ rowptr, float* __restrict__ dinv, int N) {
  __shared__ int sd[512];
  int tid = threadIdx.x;
  int idx = blockIdx.x * 512 + tid;
  int v = (idx < N) ? cnt[idx] : 0;
  sd[tid] = v;
  __syncthreads();
  for (int ofs = 1; ofs < 512; ofs <<= 1) {
    int a = (tid >= ofs) ? sd[tid - ofs] : 0;
    __syncthreads();
    sd[tid] += a;
    __syncthreads();
  }
  if (idx < N) {
    int excl = partial[blockIdx.x] + sd[tid] - v;
    rowptr[idx] = excl;
    dinv[idx] = rsqrtf((float)(v + 1));  // +1 for self loop
    if (idx == N - 1) rowptr[N] = excl + v;
  }
}

__global__ __launch_bounds__(256) void k_fill(const int* __restrict__ ei, const int* __restrict__ rowptr,
                                              int* __restrict__ cursor, const float* __restrict__ dinv,
                                              int2* __restrict__ edges, int E) {
  int e = blockIdx.x * 256 + threadIdx.x;
  if (e >= E) return;
  int s = ei[e];
  int d = ei[E + e];
  int pos = rowptr[d] + atomicAdd(&cursor[d], 1);
  edges[pos] = make_int2(s, __float_as_int(dinv[s] * dinv[d]));
}

__global__ __launch_bounds__(256) void k_gstart(const int* __restrict__ batch, int* __restrict__ start, int N) {
  int i = blockIdx.x * 256 + threadIdx.x;
  if (i >= N) return;
  int bi = batch[i];
  int prev = (i == 0) ? -1 : batch[i - 1];
  for (int g = prev + 1; g <= bi; ++g) start[g] = i;
  if (i == N - 1) {
    for (int g = bi + 1; g <= NGRAPH; ++g) start[g] = N;
  }
}

__global__ __launch_bounds__(512) void k_invcnt(const int* __restrict__ start, float* __restrict__ invcnt) {
  int g = threadIdx.x;
  if (g < NGRAPH) {
    int c = start[g + 1] - start[g];
    invcnt[g] = 1.0f / (float)max(c, 1);
  }
}

// ---------------- per-layer kernels ----------------

__device__ inline void fma4(float4& ar, float a, const float4& wv) {
  ar.x = fmaf(a, wv.x, ar.x);
  ar.y = fmaf(a, wv.y, ar.y);
  ar.z = fmaf(a, wv.z, ar.z);
  ar.w = fmaf(a, wv.w, ar.w);
}

// tmp16[32 x 128] = act(A[32 x 128]) @ W[128 x 128], stored fp16.
// act = relu(sc*a+sh) if scsh, else identity. W read straight from global (L1/L2-hot).
// Block 0 also zeroes the BN-stat accumulators (stats[0..255]).
__global__ __launch_bounds__(256) void k_gemm(const float* __restrict__ A, const float* __restrict__ Wl,
                                              const float* __restrict__ scsh,  // stats+256 | nullptr
                                              __half* __restrict__ out, float* __restrict__ stats, int N) {
  __shared__ float sH[32][DIM];
  int tid = threadIdx.x;
  if (blockIdx.x == 0) stats[tid] = 0.f;  // colsum[128], colsumsq[128]
  int row0 = blockIdx.x * 32;
#pragma unroll
  for (int i = 0; i < 4; ++i) {
    int fi = tid + i * 256;  // 0..1023 float4 slots, 32 per row
    int r = fi >> 5, c4 = fi & 31;
    int row = row0 + r;
    float4 v = make_float4(0.f, 0.f, 0.f, 0.f);
    if (row < N) v = ((const float4*)(A + (size_t)row * DIM))[c4];
    if (scsh) {
      float4 sc = ((const float4*)scsh)[c4];
      float4 sh = ((const float4*)(scsh + DIM))[c4];
      v.x = fmaxf(fmaf(v.x, sc.x, sh.x), 0.f);
      v.y = fmaxf(fmaf(v.y, sc.y, sh.y), 0.f);
      v.z = fmaxf(fmaf(v.z, sc.z, sh.z), 0.f);
      v.w = fmaxf(fmaf(v.w, sc.w, sh.w), 0.f);
    }
    ((float4*)&sH[r][0])[c4] = v;
  }
  __syncthreads();
  int ct = tid & 31, rt = tid >> 5;  // 32 col-threads x 8 row-threads
  const float4* Wv = (const float4*)Wl;  // row k -> Wv[k*32 + ct]
  float4 acc[4];
#pragma unroll
  for (int r = 0; r < 4; ++r) acc[r] = make_float4(0.f, 0.f, 0.f, 0.f);
  for (int k4 = 0; k4 < 32; ++k4) {
    float4 wv0 = Wv[(4 * k4 + 0) * 32 + ct];
    float4 wv1 = Wv[(4 * k4 + 1) * 32 + ct];
    float4 wv2 = Wv[(4 * k4 + 2) * 32 + ct];
    float4 wv3 = Wv[(4 * k4 + 3) * 32 + ct];
#pragma unroll
    for (int r = 0; r < 4; ++r) {
      float4 av = *(const float4*)&sH[rt + 8 * r][4 * k4];
      fma4(acc[r], av.x, wv0);
      fma4(acc[r], av.y, wv1);
      fma4(acc[r], av.z, wv2);
      fma4(acc[r], av.w, wv3);
    }
  }
#pragma unroll
  for (int r = 0; r < 4; ++r) {
    int row = row0 + rt + 8 * r;
    if (row < N) {
      __half2 h0 = __floats2half2_rn(acc[r].x, acc[r].y);
      __half2 h1 = __floats2half2_rn(acc[r].z, acc[r].w);
      uint2 packed = make_uint2(*(unsigned int*)&h0, *(unsigned int*)&h1);
      *(uint2*)(out + (size_t)row * DIM + 4 * ct) = packed;
    }
  }
}

// h[i] = sum_e val_e * tmp16[col_e] + dinv[i]^2 * tmp16[i] + b; BN-stat accumulation fused.
// Gather payload fp16 (4B/lane), batched 8-wide; zero-padded lanes (s=0,v=0) make the tail free.
__global__ __launch_bounds__(256) void k_agg(const __half* __restrict__ tmp16, const int* __restrict__ rowptr,
                                             const int2* __restrict__ edges, const float* __restrict__ dinv,
                                             const float* __restrict__ bias, float* __restrict__ hout,
                                             float* __restrict__ stats, int N) {
  const unsigned int* __restrict__ T = (const unsigned int*)tmp16;  // half2 slots; row i -> T[i*64 + lane]
  int lane = threadIdx.x & 63;
  int wid = threadIdx.x >> 6;
  int gwave = blockIdx.x * 4 + wid;
  int nwaves = gridDim.x * 4;
  float bx = bias[2 * lane], by = bias[2 * lane + 1];
  float sum0 = 0.f, sum1 = 0.f, sq0 = 0.f, sq1 = 0.f;
  for (int i = gwave; i < N; i += nwaves) {
    float di = dinv[i];
    float self = di * di;
    unsigned int u0 = T[(size_t)i * 64 + lane];
    float2 t0 = __half22float2(*(__half2*)&u0);
    float ax = self * t0.x, ay = self * t0.y;
    int beg = rowptr[i], end = rowptr[i + 1];
    for (int e0 = beg; e0 < end; e0 += 64) {
      int e = e0 + lane;
      int s = 0;
      float v = 0.f;
      if (e < end) {
        int2 ev = edges[e];
        s = ev.x;
        v = __int_as_float(ev.y);
      }
      int m = min(64, end - e0);
      for (int j = 0; j < m; j += 8) {
        int ss[8];
        float vv[8];
#pragma unroll
        for (int q = 0; q < 8; ++q) {
          ss[q] = __shfl(s, j + q);
          vv[q] = __shfl(v, j + q);
        }
        unsigned int uu[8];
#pragma unroll
        for (int q = 0; q < 8; ++q) uu[q] = T[(size_t)ss[q] * 64 + lane];
#pragma unroll
        for (int q = 0; q < 8; ++q) {
          float2 t = __half22float2(*(__half2*)&uu[q]);
          ax = fmaf(vv[q], t.x, ax);
          ay = fmaf(vv[q], t.y, ay);
        }
      }
    }
    ax += bx;
    ay += by;
    ((float2*)(hout + (size_t)i * DIM))[lane] = make_float2(ax, ay);
    sum0 += ax;
    sum1 += ay;
    sq0 = fmaf(ax, ax, sq0);
    sq1 = fmaf(ay, ay, sq1);
  }
  __shared__ float red[256][4];
  red[threadIdx.x][0] = sum0;
  red[threadIdx.x][1] = sum1;
  red[threadIdx.x][2] = sq0;
  red[threadIdx.x][3] = sq1;
  __syncthreads();
  if (threadIdx.x < 64) {
    int l = threadIdx.x;
    float a0 = red[l][0] + red[64 + l][0] + red[128 + l][0] + red[192 + l][0];
    float a1 = red[l][1] + red[64 + l][1] + red[128 + l][1] + red[192 + l][1];
    float q0 = red[l][2] + red[64 + l][2] + red[128 + l][2] + red[192 + l][2];
    float q1 = red[l][3] + red[64 + l][3] + red[128 + l][3] + red[192 + l][3];
    atomicAdd(&stats[2 * l], a0);
    atomicAdd(&stats[2 * l + 1], a1);
    atomicAdd(&stats[DIM + 2 * l], q0);
    atomicAdd(&stats[DIM + 2 * l + 1], q1);
  }
}

__global__ __launch_bounds__(128) void k_bnstat(float* __restrict__ stats, const float* __restrict__ gamma,
                                                const float* __restrict__ beta, int N) {
  int c = threadIdx.x;
  float invN = 1.f / (float)N;
  float mu = stats[c] * invN;
  float var = stats[DIM + c] * invN - mu * mu;
  float rstd = rsqrtf(var + EPSV);
  float sc = gamma[c] * rstd;
  stats[2 * DIM + c] = sc;
  stats[3 * DIM + c] = beta[c] - mu * sc;
}

// pool mean of relu(sc*h+sh) per graph
__global__ __launch_bounds__(512) void k_pool(const float* __restrict__ h, const int* __restrict__ start,
                                              const float* __restrict__ invcnt, const float* __restrict__ scsh,
                                              float* __restrict__ pooled, int level) {
  int g = blockIdx.x;
  int s = start[g], e = start[g + 1];
  int c = threadIdx.x & 127;
  int stripe = threadIdx.x >> 7;  // 0..3
  float sc = scsh[c], sh = scsh[DIM + c];
  float acc = 0.f;
  for (int r = s + stripe; r < e; r += 4) acc += fmaxf(fmaf(h[(size_t)r * DIM + c], sc, sh), 0.f);
  __shared__ float red[4][DIM];
  red[stripe][c] = acc;
  __syncthreads();
  if (threadIdx.x < DIM) {
    float v = (red[0][c] + red[1][c] + red[2][c] + red[3][c]) * invcnt[g];
    pooled[(size_t)g * (3 * DIM) + level * DIM + c] = v;
  }
}

__global__ __launch_bounds__(512) void k_final(const float* __restrict__ pooled, const float* __restrict__ Wf,
                                               const float* __restrict__ bf, float* __restrict__ out) {
  int t = blockIdx.x * 512 + threadIdx.x;
  if (t >= NGRAPH * DIM) return;
  int j = t & (DIM - 1);
  int i = t >> 7;
  const float* prow = pooled + (size_t)i * (3 * DIM);
  float acc = bf[j];
  for (int k = 0; k < 3 * DIM; ++k) acc = fmaf(prow[k], Wf[(size_t)k * DIM + j], acc);
  out[t] = fmaxf(acc, 0.f);
}

// ---------------- launcher ----------------

extern "C" void kernel_launch(void* const* d_in, const int* in_sizes, int n_in,
                              void* d_out, int out_size, void* d_ws, size_t ws_size,
                              hipStream_t stream) {
  const float* x = (const float*)d_in[0];
  const int* ei = (const int*)d_in[1];
  const int* batch = (const int*)d_in[2];
  const float* W = (const float*)d_in[3];
  const float* b = (const float*)d_in[4];
  const float* gamma = (const float*)d_in[5];
  const float* beta = (const float*)d_in[6];
  const float* Wf = (const float*)d_in[7];
  const float* bf = (const float*)d_in[8];
  float* out = (float*)d_out;

  const int N = in_sizes[0] / DIM;   // 50000
  const int E = in_sizes[1] / 2;     // 800000

  char* base = (char*)d_ws;
  size_t off = 0;
  auto alloc = [&](size_t bytes) -> char* {
    char* p = base + off;
    off += (bytes + 255) & ~(size_t)255;
    return p;
  };
  float* h      = (float*)alloc((size_t)N * DIM * 4);
  __half* tmp16 = (__half*)alloc((size_t)N * DIM * 2);
  int* cnt      = (int*)alloc((size_t)N * 4);
  int* cursor   = (int*)alloc((size_t)N * 4);
  int* rowptr   = (int*)alloc((size_t)(N + 1) * 4);
  int* partial  = (int*)alloc(256 * 4);
  float* dinv   = (float*)alloc((size_t)N * 4);
  int2* edges   = (int2*)alloc((size_t)E * 8);
  float* stats  = (float*)alloc(4 * DIM * 4);  // colsum|colsumsq|scale|shift
  int* start    = (int*)alloc((NGRAPH + 1) * 4);
  float* invcnt = (float*)alloc(NGRAPH * 4);
  float* pooled = (float*)alloc((size_t)NGRAPH * 3 * DIM * 4);
  (void)ws_size;

  (void)hipMemsetAsync(cnt, 0, (size_t)N * 4, stream);
  (void)hipMemsetAsync(cursor, 0, (size_t)N * 4, stream);

  int nbScan = (N + 511) / 512;  // 98
  k_count<<<(E + 255) / 256, 256, 0, stream>>>(ei, cnt, E);
  k_blocksum<<<nbScan, 512, 0, stream>>>(cnt, partial, N);
  k_scanpartials<<<1, 128, 0, stream>>>(partial, nbScan);
  k_scan_write<<<nbScan, 512, 0, stream>>>(cnt, partial, rowptr, dinv, N);
  k_fill<<<(E + 255) / 256, 256, 0, stream>>>(ei, rowptr, cursor, dinv, edges, E);
  k_gstart<<<(N + 255) / 256, 256, 0, stream>>>(batch, start, N);
  k_invcnt<<<1, 512, 0, stream>>>(start, invcnt);

  int gemmGrid = (N + 31) / 32;
  for (int l = 0; l < 6; ++l) {
    const float* hin = (l == 0) ? x : h;
    const float* scsh = (l == 0) ? nullptr : stats + 2 * DIM;
    k_gemm<<<gemmGrid, 256, 0, stream>>>(hin, W + (size_t)l * DIM * DIM, scsh, tmp16, stats, N);
    k_agg<<<2048, 256, 0, stream>>>(tmp16, rowptr, edges, dinv, b + (size_t)l * DIM, h, stats, N);
    k_bnstat<<<1, 128, 0, stream>>>(stats, gamma + (size_t)l * DIM, beta + (size_t)l * DIM, N);
    if (l & 1) k_pool<<<NGRAPH, 512, 0, stream>>>(h, start, invcnt, stats + 2 * DIM, pooled, l >> 1);
  }
  k_final<<<(NGRAPH * DIM + 511) / 512, 512, 0, stream>>>(pooled, Wf, bf, out);
}